// Round 8
// baseline (900.004 us; speedup 1.0000x reference)
//
#include <hip/hip_runtime.h>

// FSU-MGU cell: exact integer reimplementation.
// Gate(b,c,t) = sum_w popc( (bits_w & pos_w) | (~bits_w & neg_w) ) + D'(t,c)
// h-gate masks live in VGPRs (global-prefetched, L1-hot) -> critical path has
// only 8 ds_read_b64 + ~100 VALU. x-gate masks staged in LDS (off-path).
// 1024 threads: lanes l, l^32 split K; combine via __shfl_xor(.,32).
// Fence-free tagged-slot h exchange ({tag|data} u64 agent atomics).

#define NBLK 256
#define NTHR 1024

// workspace layout (bytes); [0,4096) and hw region zeroed each call
#define WS_BAR_SUB   0u
#define WS_BAR_MST   1024u
#define WS_BAR_FLG   2048u
#define WS_RNGW   8192u
#define WS_RNGWI  9216u
#define WS_RNGM   10240u
#define WS_SRCB   12288u       // 4096 u16
#define WS_SRCW   20480u       // 4096*1024 u16 (end 8,409,088)
#define WS_XP     8409088u     // 64*128*32 u32 (end 9,457,664)
#define WS_HW     9457664u     // 2 region * 4 bg * 64 jt * 16 u64 = 65,536
#define WS_DT     9523200u     // 64*4096 i32 (end 10,571,776)
#define WS_MASKS  10571776u    // 64*4096*32 u64 (end 77,680,640)

struct SRng {
  unsigned mt[3][624];
  unsigned yb[3][624];
  unsigned draws[3][1248];
  int perm[3][256];
};
struct SC {
  unsigned short rows[16][1028];
  int rngw[64];
  int rngwi[64];
};
struct SL {
  unsigned long long xmask[32*34];     // x-gate masks (single-buffered)
  unsigned xb[32*34];                  // x bits, row stride 34 u32
  unsigned short hrow16[32*68];        // h bits u16[row][jt'], stride 68
  int rngm[16];
};
union SU { SRng r; SC c; SL l; };

__device__ __forceinline__ unsigned mt_temper(unsigned y){
  y ^= y >> 11;
  y ^= (y << 7)  & 0x9d2c5680u;
  y ^= (y << 15) & 0xefc60000u;
  y ^= y >> 18;
  return y;
}

__device__ void mt_regen_serial(unsigned* mt){
  for (int i = 0; i < 624; i++){
    unsigned y = (mt[i] & 0x80000000u) | (mt[(i+1)%624] & 0x7fffffffu);
    mt[i] = mt[(i+397)%624] ^ (y >> 1) ^ ((y & 1u) ? 0x9908b0dfu : 0u);
  }
}

// numpy legacy RandomState: init_genrand seeding + Fisher-Yates with masked rejection.
__device__ void rng_gen(SU* sm, int* rngw, int* rngwi, int* rngm){
  const int tid = threadIdx.x;
  const int wv = tid >> 6, lane = tid & 63;
  const bool act = (wv < 3);
  if (act && lane == 0){
    unsigned* mt = sm->r.mt[wv];
    mt[0] = (unsigned)wv;  // seeds 0,1,2
    for (int i = 1; i < 624; i++)
      mt[i] = 1812433253u * (mt[i-1] ^ (mt[i-1] >> 30)) + (unsigned)i;
  }
  __syncthreads();
  for (int r = 0; r < 2; r++){
    if (act){
      unsigned* mt = sm->r.mt[wv]; unsigned* yb = sm->r.yb[wv];
      for (int i = lane; i < 623; i += 64)
        yb[i] = (mt[i] & 0x80000000u) | (mt[i+1] & 0x7fffffffu);
    }
    __syncthreads();
    if (act){
      unsigned* mt = sm->r.mt[wv]; unsigned* yb = sm->r.yb[wv];
      for (int i = lane; i < 227; i += 64){
        unsigned y = yb[i];
        mt[i] = mt[i+397] ^ (y >> 1) ^ ((y & 1u) ? 0x9908b0dfu : 0u);
      }
    }
    __syncthreads();
    if (act){
      unsigned* mt = sm->r.mt[wv]; unsigned* yb = sm->r.yb[wv];
      for (int i = 227 + lane; i < 454; i += 64){
        unsigned y = yb[i];
        mt[i] = mt[i-227] ^ (y >> 1) ^ ((y & 1u) ? 0x9908b0dfu : 0u);
      }
    }
    __syncthreads();
    if (act){
      unsigned* mt = sm->r.mt[wv]; unsigned* yb = sm->r.yb[wv];
      for (int i = 454 + lane; i < 624; i += 64){
        unsigned y = (i < 623) ? yb[i]
                   : ((mt[623] & 0x80000000u) | (mt[0] & 0x7fffffffu));
        mt[i] = mt[i-227] ^ (y >> 1) ^ ((y & 1u) ? 0x9908b0dfu : 0u);
      }
    }
    __syncthreads();
    if (act){
      unsigned* mt = sm->r.mt[wv];
      for (int i = lane; i < 624; i += 64)
        sm->r.draws[wv][r*624 + i] = mt_temper(mt[i]);
    }
    __syncthreads();
  }
  if (act && lane == 0){
    const int n = (wv == 2) ? 16 : 256;
    int* perm = sm->r.perm[wv];
    for (int i = 0; i < n; i++) perm[i] = i;
    int dp = 0, spos = 624;
    unsigned* mt = sm->r.mt[wv];
    for (int i = n - 1; i > 0; i--){
      unsigned mask = (unsigned)i;
      mask |= mask >> 1; mask |= mask >> 2; mask |= mask >> 4;
      mask |= mask >> 8; mask |= mask >> 16;
      unsigned v;
      do {
        unsigned d;
        if (dp < 1248) d = sm->r.draws[wv][dp++];
        else {
          if (spos >= 624){ mt_regen_serial(mt); spos = 0; }
          d = mt_temper(mt[spos++]);
        }
        v = d & mask;
      } while (v > (unsigned)i);
      int tmp = perm[i]; perm[i] = perm[v]; perm[v] = tmp;
    }
    int* dst = (wv == 0) ? rngw : (wv == 1) ? rngwi : rngm;
    for (int i = 0; i < n; i++) dst[i] = perm[i];
  }
}

// full-grid barrier WITH fences — setup phases only
__device__ __forceinline__ void gbar_full(unsigned char* ws, unsigned ep){
  __syncthreads();
  if (threadIdx.x == 0){
    __threadfence();
    unsigned* sub = (unsigned*)(ws + WS_BAR_SUB + (blockIdx.x & 7)*128);
    unsigned old = atomicAdd(sub, 1u);
    if (old == ep*32u - 1u){
      unsigned* mst = (unsigned*)(ws + WS_BAR_MST);
      unsigned mo = atomicAdd(mst, 1u);
      if (mo == ep*8u - 1u){
        for (int i = 0; i < 8; i++)
          __hip_atomic_store((unsigned*)(ws + WS_BAR_FLG + i*128), ep,
                             __ATOMIC_RELAXED, __HIP_MEMORY_SCOPE_AGENT);
      }
    }
    const unsigned* fl = (const unsigned*)(ws + WS_BAR_FLG + (blockIdx.x & 7)*128);
    while (__hip_atomic_load(fl, __ATOMIC_RELAXED, __HIP_MEMORY_SCOPE_AGENT) < ep)
      __builtin_amdgcn_s_sleep(8);
  }
  __syncthreads();
  __threadfence();
}

__device__ __forceinline__ int clampi(int v){
  v = v < -512 ? -512 : v;
  v = v >  512 ?  512 : v;
  return v;
}

// (x & p) | (~x & n)  ->  v_bfi_b32
__device__ __forceinline__ unsigned bfi(unsigned x, unsigned p, unsigned n){
  return (x & p) | (~x & n);
}

__global__ void __launch_bounds__(NTHR)
fsu_kernel(const float* __restrict__ x, const float* __restrict__ hx0,
           const float* __restrict__ wih, const float* __restrict__ bih,
           const float* __restrict__ whh, const float* __restrict__ bhh,
           float* __restrict__ out, unsigned char* __restrict__ ws)
{
  __shared__ SU sm;
  const int tid = threadIdx.x;
  const int bid = blockIdx.x;

  int* rngw  = (int*)(ws + WS_RNGW);
  int* rngwi = (int*)(ws + WS_RNGWI);
  int* rngm  = (int*)(ws + WS_RNGM);
  unsigned short* srcb = (unsigned short*)(ws + WS_SRCB);
  unsigned short* srcw = (unsigned short*)(ws + WS_SRCW);
  unsigned* xp   = (unsigned*)(ws + WS_XP);
  unsigned long long* hw = (unsigned long long*)(ws + WS_HW);
  int* Dt = (int*)(ws + WS_DT);
  unsigned long long* masks = (unsigned long long*)(ws + WS_MASKS);

  // ---------- phase 0: RNG tables (block 0) || bit-pack + src build (others)
  if (bid == 0){
    rng_gen(&sm, rngw, rngwi, rngm);
  } else {
    const int gtid = (bid - 1)*NTHR + tid;
    const int lane = tid & 63;
    const int gw = gtid >> 6;
    const int nw = (NBLK-1)*(NTHR/64);
    const int nthr = (NBLK-1)*NTHR;
    for (int ch = gw; ch < 131072; ch += nw){            // x bits
      float v = x[(size_t)ch*64 + lane];
      unsigned long long bal = __ballot(v != 0.0f);
      if ((lane & 31) == 0) xp[ch*2 + (lane >> 5)] = (unsigned)(bal >> lane);
    }
    for (int idx = gtid; idx < 4096; idx += nthr){       // initial h slots (region 0, tag 0)
      int bg2 = idx >> 10, jt2 = (idx >> 4) & 63, rp2 = idx & 15;
      int r0 = bg2*32 + 2*rp2;
      unsigned v = 0;
      for (int j = 0; j < 16; j++){
        v |= (hx0[(size_t)r0*1024 + jt2*16 + j] != 0.0f) ? (1u<<j) : 0u;
        v |= (hx0[(size_t)(r0+1)*1024 + jt2*16 + j] != 0.0f) ? (1u<<(16+j)) : 0u;
      }
      hw[idx] = (unsigned long long)v;  // tag 0; flushed by gbar_full fence
    }
    for (int idx = gtid; idx < 4096*1024; idx += nthr){  // src = round((clip+1)*128)
      int c = idx >> 10, k = idx & 1023;
      float wv2 = (c < 2048) ? wih[(size_t)c*1024 + k] : whh[(size_t)(c - 2048)*1024 + k];
      float cl = fminf(fmaxf(wv2, -1.0f), 1.0f);
      srcw[idx] = (unsigned short)(int)rintf((cl + 1.0f)*0.5f*256.0f);
    }
    for (int c = gtid; c < 4096; c += nthr){
      float bv = (c < 2048) ? bih[c] : bhh[c - 2048];
      float cl = fminf(fmaxf(bv, -1.0f), 1.0f);
      srcb[c] = (unsigned short)(int)rintf((cl + 1.0f)*0.5f*256.0f);
    }
  }
  gbar_full(ws, 1u);

  // ---------- phase C: pos/neg masks + D' constants (popc(neg) folded in)
  {
    const int c0 = bid * 16;
    const unsigned* srcw32 = (const unsigned*)srcw;
    for (int q = tid; q < 16*512; q += NTHR){
      int r = q >> 9, w = q & 511;
      ((unsigned*)&sm.c.rows[r][0])[w] = srcw32[(size_t)(c0 + r)*512 + w];
    }
    if (tid < 64) sm.c.rngw[tid] = rngw[tid];
    if (tid >= 64 && tid < 128) sm.c.rngwi[tid - 64] = rngwi[tid - 64];
    __syncthreads();
    for (int row = tid; row < 1024; row += NTHR){   // (t, local col)
      int t = row >> 4, lc = row & 15, col = c0 + lc;
      int rp = sm.c.rngw[t], ri = sm.c.rngwi[t];
      int hi = rp > ri ? rp : ri;
      int lo1 = (rp < ri ? rp : ri) + 1;
      bool rihi = (ri >= rp);
      const unsigned* srow = (const unsigned*)&sm.c.rows[lc][0];
      unsigned long long* gdst = masks + ((size_t)t*4096 + col)*32;
      int cnti = 0, cntn = 0;
      for (int w = 0; w < 32; w++){
        unsigned pos = 0, neg = 0;
        #pragma unroll
        for (int i2 = 15; i2 >= 0; i2--){
          unsigned v2 = srow[w*16 + i2];
          int vH = (int)(v2 >> 16);
          int vL = (int)(v2 & 0xFFFFu);
          pos = (pos << 1) | ((unsigned)(hi - vH) >> 31);   // v > hi
          neg = (neg << 1) | ((unsigned)(vH - lo1) >> 31);  // v <= lo
          pos = (pos << 1) | ((unsigned)(hi - vL) >> 31);
          neg = (neg << 1) | ((unsigned)(vL - lo1) >> 31);
        }
        gdst[w] = (unsigned long long)pos | ((unsigned long long)neg << 32);
        cnti += rihi ? __popc(pos) : (32 - __popc(neg));    // count(src > ri)
        cntn += __popc(neg);
      }
      Dt[t*4096 + col] = 1024 - cnti - cntn + (((int)srcb[col] > rp) ? 1 : 0);
    }
  }
  gbar_full(ws, 2u);

  // ---------- main recurrence
  const int jt = bid & 63, bg = bid >> 6;
  const int j0 = jt * 16, b0 = bg * 32;
  const int kh  = (tid >> 5) & 1;
  const int o   = ((tid >> 6) << 5) + (tid & 31);   // 0..511
  const int b_l = o >> 4, j_l = o & 15;
  const int bglob = b0 + b_l;
  const int w2lo = kh << 3;

  int hcur = (hx0[(size_t)bglob*1024 + j0 + j_l] != 0.0f) ? 1 : 0;
  int A1=0,A2=0,A3=0,A4=0,A5=0,A6=0;
  unsigned sr1=10u, sr2=10u, sr3=10u;
  int i1p=0,i1i=0,i2p=0,i2i=0,i3p=0,i3i=0;

  if (tid < 16) sm.l.rngm[tid] = rngm[tid];

  const unsigned* msrc = (const unsigned*)masks;
  int xgf, xgn, dhf, dhn;
  unsigned mreg[2], xreg;       // x-mask / x-bits prefetch (next tile)
  int dreg[4];
  uint4 hmA[8], hmB[8];         // h-gate masks in VGPRs (half-K each)

  // per-thread global bases for h-mask fragments (cols 2048+j, 3072+j)
  const uint4* hmbaseA = (const uint4*)(masks + ((size_t)(2048 + j0 + j_l))*32 + (kh << 4));
  const uint4* hmbaseB = (const uint4*)(masks + ((size_t)(3072 + j0 + j_l))*32 + (kh << 4));
  const size_t hstep = (size_t)4096*32/2;   // uint4 units per t (4096 cols * 32 u64 / 2)

  // ---- prime: stage t=0, initial h, x-popc(0), hmask(0), prefetch t=1
  {
    unsigned* xm = (unsigned*)sm.l.xmask;
    #pragma unroll
    for (int i = 0; i < 2; i++){
      int q = tid + i*NTHR;
      int r = q >> 6, qq = q & 63;
      int c = (r >> 4)*1024 + j0 + (r & 15);      // gates 0,1
      xm[r*68 + qq] = msrc[((size_t)0*4096 + c)*64 + qq];
    }
    {
      int bb = tid >> 5, w = tid & 31;
      sm.l.xb[bb*34 + w] = xp[((size_t)0*128 + b0 + bb)*32 + w];
    }
    {
      unsigned long long v = __hip_atomic_load(&hw[(size_t)bg*1024 + tid],
                                               __ATOMIC_RELAXED,
                                               __HIP_MEMORY_SCOPE_AGENT);
      int jt_ = tid >> 4, rp_ = tid & 15;
      unsigned data = (unsigned)v;
      sm.l.hrow16[(2*rp_)*68 + jt_]   = (unsigned short)(data & 0xFFFFu);
      sm.l.hrow16[(2*rp_+1)*68 + jt_] = (unsigned short)(data >> 16);
    }
    #pragma unroll
    for (int g = 0; g < 4; g++) dreg[g] = Dt[0*4096 + g*1024 + j0 + j_l];
    // h-gate masks for t=0 -> regs
    #pragma unroll
    for (int i = 0; i < 8; i++){ hmA[i] = hmbaseA[i]; hmB[i] = hmbaseB[i]; }
    __syncthreads();
    // x-popc for t=0
    int s0=0, s1=0;
    const uint2* xrow = (const uint2*)&sm.l.xb[b_l*34];
    const ulonglong2* m0p = (const ulonglong2*)&sm.l.xmask[(0  + j_l)*34];
    const ulonglong2* m1p = (const ulonglong2*)&sm.l.xmask[(16 + j_l)*34];
    #pragma unroll
    for (int w2i = 0; w2i < 8; w2i++){
      int w2 = w2lo + w2i;
      uint2 xv = xrow[w2];
      ulonglong2 a = m0p[w2];
      s0 += __popc(bfi(xv.x, (unsigned)a.x, (unsigned)(a.x >> 32)));
      s0 += __popc(bfi(xv.y, (unsigned)a.y, (unsigned)(a.y >> 32)));
      ulonglong2 b = m1p[w2];
      s1 += __popc(bfi(xv.x, (unsigned)b.x, (unsigned)(b.x >> 32)));
      s1 += __popc(bfi(xv.y, (unsigned)b.y, (unsigned)(b.y >> 32)));
    }
    s0 += __shfl_xor(s0, 32);
    s1 += __shfl_xor(s1, 32);
    xgf = dreg[0] + s0;
    xgn = dreg[1] + s1;
    dhf = dreg[2]; dhn = dreg[3];
    // prefetch x-tile t=1
    #pragma unroll
    for (int i = 0; i < 2; i++){
      int q = tid + i*NTHR;
      int r = q >> 6, qq = q & 63;
      int c = (r >> 4)*1024 + j0 + (r & 15);
      mreg[i] = msrc[((size_t)1*4096 + c)*64 + qq];
    }
    {
      int bb = tid >> 5, w = tid & 31;
      xreg = xp[((size_t)1*128 + b0 + bb)*32 + w];
    }
    #pragma unroll
    for (int g = 0; g < 4; g++) dreg[g] = Dt[1*4096 + g*1024 + j0 + j_l];
  }

  for (int t = 0; t < 64; t++){
    const int par = t & 1;

    // ---- h-gate popc from VGPR masks + LDS h-words (critical path)
    int s2=0, s3=0;
    {
      const uint2* hrow = (const uint2*)&sm.l.hrow16[b_l*68];
      #pragma unroll
      for (int w2i = 0; w2i < 8; w2i++){
        uint2 hv = hrow[w2lo + w2i];
        s2 += __popc(bfi(hv.x, hmA[w2i].x, hmA[w2i].y));
        s2 += __popc(bfi(hv.y, hmA[w2i].z, hmA[w2i].w));
        s3 += __popc(bfi(hv.x, hmB[w2i].x, hmB[w2i].y));
        s3 += __popc(bfi(hv.y, hmB[w2i].z, hmB[w2i].w));
      }
    }
    s2 += __shfl_xor(s2, 32);
    s3 += __shfl_xor(s3, 32);
    const int g_hf = dhf + s2;
    const int g_hn = dhn + s3;

    // issue h-mask loads for t+1 (L1-hot; land under FSU/publish/pull)
    if (t < 63){
      const uint4* pA = hmbaseA + (size_t)(t+1)*hstep;
      const uint4* pB = hmbaseB + (size_t)(t+1)*hstep;
      #pragma unroll
      for (int i = 0; i < 8; i++){ hmA[i] = pA[i]; hmB[i] = pB[i]; }
    }

    // ---- FSU elementwise chain (exact, 2x-scaled ints; dup on l, l^32)
    int s1v = xgf + g_hf;
    A1 = clampi(A1 + 2*s1v - 2049);
    int fg_in = (A1 >= 2); A1 -= fg_in << 1;
    A2 = clampi(A2 + ((fg_in + 1) << 1));
    int fg = (A2 >= 4); A2 -= fg << 2;
    A3 = clampi(A3 + (g_hn << 1) - 1024);
    int hnb = (A3 >= 2); A3 -= hnb << 1;

    sr1 = ((sr1 >> 1) | ((unsigned)hnb << 3)) & 0xFu;
    int ng_prod;
    {
      int cv = __popc(sr1) << 2;
      int bp = cv > sm.l.rngm[i1p & 15];
      int bi = cv > sm.l.rngm[i1i & 15];
      ng_prod = fg ? bp : (1 - bi);
      i1p += fg; i1i += 1 - fg;
    }
    A4 = clampi(A4 + (xgn << 1) - 1024);
    int inb = (A4 >= 2); A4 -= inb << 1;
    A5 = clampi(A5 + ((inb + ng_prod) << 1) - 1);
    int ng = (A5 >= 2); A5 -= ng << 1;

    sr2 = ((sr2 >> 1) | ((unsigned)ng << 3)) & 0xFu;
    int fgi;
    {
      int cv = __popc(sr2) << 2;
      int bp = cv > sm.l.rngm[i2p & 15];
      int bi = cv > sm.l.rngm[i2i & 15];
      fgi = (1 - fg) ? bp : (1 - bi);
      i2p += 1 - fg; i2i += fg;
    }
    sr3 = ((sr3 >> 1) | ((unsigned)hcur << 3)) & 0xFu;
    int fgp;
    {
      int cv = __popc(sr3) << 2;
      int bp = cv > sm.l.rngm[i3p & 15];
      int bi = cv > sm.l.rngm[i3i & 15];
      fgp = fg ? bp : (1 - bi);
      i3p += fg; i3i += 1 - fg;
    }
    A6 = clampi(A6 + ((ng + fgi + fgp) << 1) - 2);
    int hy = (A6 >= 2); A6 -= hy << 1;
    hcur = hy;

    if (t < 63){
      unsigned long long bal = __ballot(hy);
      if ((tid & 63) == 0){
        unsigned data = (unsigned)bal;
        unsigned long long val = (unsigned long long)data
                               | ((unsigned long long)(unsigned)(t + 1) << 32);
        __hip_atomic_store(
            &hw[(((size_t)((par ^ 1)*4 + bg))*64 + jt)*16 + (tid >> 6)], val,
            __ATOMIC_RELAXED, __HIP_MEMORY_SCOPE_AGENT);
      }
    }
    if (kh == 0)
      out[(size_t)t*131072 + (size_t)bglob*1024 + j0 + j_l] = (float)hy;
    if (t == 63) break;

    // commit prefetched x-tile (single buffer; prev readers done pre-B2)
    {
      unsigned* xm = (unsigned*)sm.l.xmask;
      #pragma unroll
      for (int i = 0; i < 2; i++){
        int q = tid + i*NTHR;
        int r = q >> 6, qq = q & 63;
        xm[r*68 + qq] = mreg[i];
      }
      int bb = tid >> 5, w = tid & 31;
      sm.l.xb[bb*34 + w] = xreg;
    }
    __syncthreads();   // B1

    // x-popc for t+1
    {
      int s0=0, s1b=0;
      const uint2* xrow = (const uint2*)&sm.l.xb[b_l*34];
      const ulonglong2* m0p = (const ulonglong2*)&sm.l.xmask[(0  + j_l)*34];
      const ulonglong2* m1p = (const ulonglong2*)&sm.l.xmask[(16 + j_l)*34];
      #pragma unroll
      for (int w2i = 0; w2i < 8; w2i++){
        int w2 = w2lo + w2i;
        uint2 xv = xrow[w2];
        ulonglong2 a = m0p[w2];
        s0 += __popc(bfi(xv.x, (unsigned)a.x, (unsigned)(a.x >> 32)));
        s0 += __popc(bfi(xv.y, (unsigned)a.y, (unsigned)(a.y >> 32)));
        ulonglong2 b = m1p[w2];
        s1b += __popc(bfi(xv.x, (unsigned)b.x, (unsigned)(b.x >> 32)));
        s1b += __popc(bfi(xv.y, (unsigned)b.y, (unsigned)(b.y >> 32)));
      }
      s0 += __shfl_xor(s0, 32);
      s1b += __shfl_xor(s1b, 32);
      xgf = dreg[0] + s0;
      xgn = dreg[1] + s1b;
      dhf = dreg[2]; dhn = dreg[3];
    }

    // issue x-tile prefetch for t+2
    if (t < 62){
      #pragma unroll
      for (int i = 0; i < 2; i++){
        int q = tid + i*NTHR;
        int r = q >> 6, qq = q & 63;
        int c = (r >> 4)*1024 + j0 + (r & 15);
        mreg[i] = msrc[((size_t)(t+2)*4096 + c)*64 + qq];
      }
      {
        int bb = tid >> 5, w = tid & 31;
        xreg = xp[((size_t)(t+2)*128 + b0 + bb)*32 + w];
      }
      #pragma unroll
      for (int g = 0; g < 4; g++)
        dreg[g] = Dt[(t+2)*4096 + g*1024 + j0 + j_l];
    }

    // pull h(t+1): one tagged slot per thread, tag-spin
    {
      const unsigned ep = (unsigned)(t + 1);
      const unsigned long long* slot =
          &hw[((size_t)((par ^ 1)*4 + bg))*1024 + tid];
      unsigned long long v = __hip_atomic_load(slot, __ATOMIC_RELAXED,
                                               __HIP_MEMORY_SCOPE_AGENT);
      while ((unsigned)(v >> 32) < ep){
        __builtin_amdgcn_s_sleep(2);
        v = __hip_atomic_load(slot, __ATOMIC_RELAXED,
                              __HIP_MEMORY_SCOPE_AGENT);
      }
      int jt_ = tid >> 4, rp_ = tid & 15;
      unsigned data = (unsigned)v;
      sm.l.hrow16[(2*rp_)*68 + jt_]   = (unsigned short)(data & 0xFFFFu);
      sm.l.hrow16[(2*rp_+1)*68 + jt_] = (unsigned short)(data >> 16);
    }
    __syncthreads();   // B2
  }
}

extern "C" void kernel_launch(void* const* d_in, const int* in_sizes, int n_in,
                              void* d_out, int out_size, void* d_ws, size_t ws_size,
                              hipStream_t stream)
{
  (void)in_sizes; (void)n_in; (void)out_size; (void)ws_size;
  const float* x   = (const float*)d_in[0];
  const float* hx0 = (const float*)d_in[1];
  const float* wih = (const float*)d_in[2];
  const float* bih = (const float*)d_in[3];
  const float* whh = (const float*)d_in[4];
  const float* bhh = (const float*)d_in[5];
  float* out = (float*)d_out;
  unsigned char* ws = (unsigned char*)d_ws;

  hipMemsetAsync(d_ws, 0, 4096, stream);
  hipMemsetAsync(ws + WS_HW, 0, 65536, stream);

  void* args[] = { (void*)&x, (void*)&hx0, (void*)&wih, (void*)&bih,
                   (void*)&whh, (void*)&bhh, (void*)&out, (void*)&ws };
  hipLaunchCooperativeKernel(reinterpret_cast<void*>(fsu_kernel),
                             dim3(NBLK), dim3(NTHR), args, 0, stream);
}